// Round 4
// baseline (388.430 us; speedup 1.0000x reference)
//
#include <hip/hip_runtime.h>
#include <hip/hip_cooperative_groups.h>
#include <math.h>

namespace cg = cooperative_groups;

// Problem constants (match reference)
#define BATCH 8192
#define DIM   1024
#define GRP   8
#define NBLK  1024                     // co-resident: 4 blocks/CU x 256 CUs
#define ROWS_PER_BLK (BATCH / NBLK)    // 8 rows per block
constexpr float EPS   = 1e-12f;
constexpr float INV_N = 1.0f / (float(BATCH) * float(DIM)); // 1 / 8388608

typedef float floatx4 __attribute__((ext_vector_type(4)));  // native vec for nt-store

// ---------------------------------------------------------------------------
// Single cooperative kernel:
//   phase 1: each block loads its 8 rows into REGISTERS, block-sums -> ws[bid]
//   grid.sync()
//   phase 2: each block reduces the 1024 partials (L2-hit) -> global mean,
//            relu(x-mean) on register-held data, per-row L2 norm via
//            32-lane half-wave shuffles, scale by sigmoid(wp), write G=8
//            tiled copies with nontemporal float4 stores.
// xf is read from HBM exactly once; output written once. One dispatch.
// ---------------------------------------------------------------------------
__global__ __launch_bounds__(256, 4)
void fused_kernel(const float* __restrict__ xf,
                  const float* __restrict__ wp,
                  float* __restrict__ ws,
                  float* __restrict__ out) {
    const int tid       = threadIdx.x;       // 0..255
    const int bid       = blockIdx.x;        // 0..1023
    const int row_local = tid >> 5;          // 0..7  (8 rows/block)
    const int lane32    = tid & 31;          // 0..31 (32 threads/row)
    const int row       = bid * ROWS_PER_BLK + row_local;
    const int lane      = tid & 63;
    const int wave      = tid >> 6;

    // ---- phase 1: load 8 float4 of my row into registers, block sum -------
    const float4* xr = reinterpret_cast<const float4*>(xf + (size_t)row * DIM);
    float4 v[8];
    float s = 0.0f;
    #pragma unroll
    for (int k = 0; k < 8; ++k) {
        v[k] = xr[lane32 + 32 * k];          // wave: 2x 512B contiguous segs
        s += (v[k].x + v[k].y) + (v[k].z + v[k].w);
    }
    #pragma unroll
    for (int off = 32; off > 0; off >>= 1)
        s += __shfl_down(s, off, 64);

    __shared__ float sm[4];
    if (lane == 0) sm[wave] = s;
    __syncthreads();
    if (tid == 0) ws[bid] = (sm[0] + sm[1]) + (sm[2] + sm[3]);

    cg::this_grid().sync();

    // ---- phase 2a: reduce 1024 partials -> mean (each block, L2-hit) ------
    const float4* w4 = reinterpret_cast<const float4*>(ws);
    float4 pw = w4[tid];                     // 256 threads x float4 = 1024
    float p = (pw.x + pw.y) + (pw.z + pw.w);
    #pragma unroll
    for (int off = 32; off > 0; off >>= 1)
        p += __shfl_down(p, off, 64);

    __shared__ float sm2[4];
    __shared__ float s_mean;
    if (lane == 0) sm2[wave] = p;
    __syncthreads();
    if (tid == 0)
        s_mean = ((sm2[0] + sm2[1]) + (sm2[2] + sm2[3])) * INV_N;
    __syncthreads();
    const float mean = s_mean;

    // ---- phase 2b: relu(x-mean), per-row sum of squares -------------------
    float q = 0.0f;
    #pragma unroll
    for (int k = 0; k < 8; ++k) {
        v[k].x = fmaxf(v[k].x - mean, 0.0f);
        v[k].y = fmaxf(v[k].y - mean, 0.0f);
        v[k].z = fmaxf(v[k].z - mean, 0.0f);
        v[k].w = fmaxf(v[k].w - mean, 0.0f);
        q += v[k].x * v[k].x + v[k].y * v[k].y
           + v[k].z * v[k].z + v[k].w * v[k].w;
    }
    // 32-lane half-wave reduce: masks 1..16 stay within each 32-lane half,
    // so lanes 0-31 (row A) and 32-63 (row B) reduce independently.
    #pragma unroll
    for (int off = 16; off > 0; off >>= 1)
        q += __shfl_xor(q, off, 64);

    const float norm  = fmaxf(sqrtf(q), EPS);
    const float sig   = 1.0f / (1.0f + expf(-wp[0]));
    const float scale = sig / norm;

    // ---- phase 2c: write 8 tiled copies, nontemporal float4 stores --------
    floatx4* orow = reinterpret_cast<floatx4*>(out + (size_t)row * (GRP * DIM));
    #pragma unroll
    for (int k = 0; k < 8; ++k) {
        floatx4 o;
        o.x = v[k].x * scale;
        o.y = v[k].y * scale;
        o.z = v[k].z * scale;
        o.w = v[k].w * scale;
        #pragma unroll
        for (int g = 0; g < GRP; ++g)
            __builtin_nontemporal_store(o, &orow[g * 256 + k * 32 + lane32]);
    }
}

// ---------------------------------------------------------------------------
extern "C" void kernel_launch(void* const* d_in, const int* in_sizes, int n_in,
                              void* d_out, int out_size, void* d_ws, size_t ws_size,
                              hipStream_t stream) {
    const float* xf = (const float*)d_in[0];   // [8192,1024] fp32
    const float* wp = (const float*)d_in[1];   // [1] fp32
    // d_in[2] is W_tile = kron(ones(1,8), eye(1024)) -> output is 8 tiled
    // copies of the normalized row; no GEMM needed.
    float* out = (float*)d_out;                // [8192, 8192] fp32
    float* ws  = (float*)d_ws;                 // ws[0..1023] partial sums

    void* args[] = { (void*)&xf, (void*)&wp, (void*)&ws, (void*)&out };
    hipLaunchCooperativeKernel((const void*)fused_kernel,
                               dim3(NBLK), dim3(256), args, 0, stream);
}

// Round 5
// 302.578 us; speedup vs baseline: 1.2837x; 1.2837x over previous
//
#include <hip/hip_runtime.h>
#include <math.h>

// Problem constants (match reference)
#define BATCH 8192
#define DIM   1024
#define GRP   8
#define NPART 256                         // number of partial sums in ws
constexpr float EPS   = 1e-12f;
constexpr float INV_N = 1.0f / (float(BATCH) * float(DIM)); // 1 / 8388608

typedef float floatx4 __attribute__((ext_vector_type(4)));  // native vec for nt-store

// ---------------------------------------------------------------------------
// R4 post-mortem note: a fused hipLaunchCooperativeKernel version (grid.sync
// between mean and use) regressed 301.8 -> 388.4 us. The grid barrier
// serializes read-phase and write-phase across the whole GPU and its
// cross-XCD atomic traffic is expensive; stream-ordered two-kernel dispatch
// overlaps late loads with early stores and is ~90 us faster. Keep 2 kernels.
// ---------------------------------------------------------------------------

// ---------------------------------------------------------------------------
// Kernel A: partial sums of xf -> ws[0..255]. 256 blocks x 1024 threads,
// each thread sums 8 float4s (fully unrolled), block reduce, one store.
// All 256 slots are overwritten, so no zero-init of ws is needed.
// ---------------------------------------------------------------------------
__global__ __launch_bounds__(1024)
void partial_sum_kernel(const float* __restrict__ xf,
                        float* __restrict__ ws) {
    const int tid = threadIdx.x;
    const int gid = blockIdx.x * 1024 + tid;           // 0 .. 262143
    const float4* x4 = reinterpret_cast<const float4*>(xf);
    // total float4 = 2097152 ; stride between a thread's loads = 262144
    float s = 0.0f;
    #pragma unroll
    for (int i = 0; i < 8; ++i) {
        float4 v = x4[gid + i * 262144];
        s += (v.x + v.y) + (v.z + v.w);
    }
    #pragma unroll
    for (int off = 32; off > 0; off >>= 1)
        s += __shfl_down(s, off, 64);

    __shared__ float sm[16];                           // 1024 threads = 16 waves
    const int lane = tid & 63;
    const int wave = tid >> 6;
    if (lane == 0) sm[wave] = s;
    __syncthreads();
    if (tid == 0) {
        float t = 0.0f;
        #pragma unroll
        for (int w = 0; w < 16; ++w) t += sm[w];
        ws[blockIdx.x] = t;
    }
}

// ---------------------------------------------------------------------------
// Kernel B: per-row relu(x-mean), L2 normalize, scale by sigmoid(wp),
// write G=8 tiled copies with nontemporal float4 stores.
// One 256-thread block per row. Reduces the 256 partials itself (L2-hit).
// ---------------------------------------------------------------------------
__global__ __launch_bounds__(256)
void norm_tile_kernel(const float* __restrict__ xf,
                      const float* __restrict__ wp,
                      const float* __restrict__ ws,
                      float* __restrict__ out) {
    const int row = blockIdx.x;
    const int tid = threadIdx.x;                       // 0..255

    // Issue the row load early so it overlaps the partial-sum reduction.
    const float4* xr = reinterpret_cast<const float4*>(xf + (size_t)row * DIM);
    float4 v = xr[tid];

    // Reduce the 256 partial sums -> global mean.
    float p = ws[tid];
    #pragma unroll
    for (int off = 32; off > 0; off >>= 1)
        p += __shfl_down(p, off, 64);

    __shared__ float sm[4];
    __shared__ float red[2];
    const int lane = tid & 63;
    const int wave = tid >> 6;
    if (lane == 0) sm[wave] = p;
    __syncthreads();
    if (tid == 0) red[0] = (sm[0] + sm[1]) + (sm[2] + sm[3]);
    __syncthreads();
    const float mean = red[0] * INV_N;

    // ReLU(x - mean) and row sum of squares.
    v.x = fmaxf(v.x - mean, 0.0f);
    v.y = fmaxf(v.y - mean, 0.0f);
    v.z = fmaxf(v.z - mean, 0.0f);
    v.w = fmaxf(v.w - mean, 0.0f);

    float s = v.x * v.x + v.y * v.y + v.z * v.z + v.w * v.w;
    #pragma unroll
    for (int off = 32; off > 0; off >>= 1)
        s += __shfl_down(s, off, 64);
    if (lane == 0) sm[wave] = s;                       // safe: after barrier above
    __syncthreads();
    if (tid == 0) red[1] = (sm[0] + sm[1]) + (sm[2] + sm[3]);
    __syncthreads();

    const float norm  = fmaxf(sqrtf(red[1]), EPS);
    const float sig   = 1.0f / (1.0f + expf(-wp[0]));
    const float scale = sig / norm;

    floatx4 o;
    o.x = v.x * scale;
    o.y = v.y * scale;
    o.z = v.z * scale;
    o.w = v.w * scale;

    // 8 tiled copies, nontemporal streaming stores (no reuse of out).
    floatx4* orow = reinterpret_cast<floatx4*>(out + (size_t)row * (GRP * DIM));
    #pragma unroll
    for (int g = 0; g < GRP; ++g)
        __builtin_nontemporal_store(o, &orow[g * (DIM / 4) + tid]);
}

// ---------------------------------------------------------------------------
extern "C" void kernel_launch(void* const* d_in, const int* in_sizes, int n_in,
                              void* d_out, int out_size, void* d_ws, size_t ws_size,
                              hipStream_t stream) {
    const float* xf = (const float*)d_in[0];   // [8192,1024] fp32
    const float* wp = (const float*)d_in[1];   // [1] fp32
    // d_in[2] is W_tile = kron(ones(1,8), eye(1024)) -> output is 8 tiled
    // copies of the normalized row; no GEMM needed.
    float* out = (float*)d_out;                // [8192, 8192] fp32
    float* ws  = (float*)d_ws;                 // ws[0..255] partial sums

    partial_sum_kernel<<<NPART, 1024, 0, stream>>>(xf, ws);
    norm_tile_kernel<<<BATCH, 256, 0, stream>>>(xf, wp, ws, out);
}